// Round 16
// baseline (776.440 us; speedup 1.0000x reference)
//
#include <hip/hip_runtime.h>
#include <hip/hip_bf16.h>

#define NN 100000
#define DIN 128
#define DOUT 256
#define RR 4
#define EE 600000
#define NB (RR * NN)
#define SCAN_BLKS 400
#define SCAN_CHUNK 1000
#define PBLKS 2048          // CSR-build blocks; bid&7 = XCD partition (round-robin map)

typedef __attribute__((ext_vector_type(4))) float f32x4;
typedef __attribute__((ext_vector_type(8))) short short8;
typedef __attribute__((ext_vector_type(2))) uint uint2v;

__device__ __forceinline__ float bf2f(ushort u) {
    union { unsigned int i; float f; } v; v.i = ((unsigned int)u) << 16; return v.f;
}
__device__ __forceinline__ ushort f2bf(float f) {
    union { float f; unsigned int i; } v; v.f = f;
    unsigned int r = v.i + 0x7fff + ((v.i >> 16) & 1);  // RNE
    return (ushort)(r >> 16);
}

__device__ __forceinline__ void ld_g2l16(const void* g, void* l) {
    __builtin_amdgcn_global_load_lds(
        (const __attribute__((address_space(1))) void*)g,
        (__attribute__((address_space(3))) void*)l, 16, 0, 0);
}

// ---------------- consolidated weight/bias prep ----------------
// W layout (r11-proven, SWIZZLED for LDS-staged B): logical W[kd][o] = 0.25*sum;
// block kd>>6, chunk c=(kd>>3)&7 stored at slot c^(o&7), elem kd&7.
__device__ __forceinline__ void store_w(ushort* W, int kd, int o, float s) {
    int cs = ((kd >> 3) & 7) ^ (o & 7);
    W[((size_t)(kd >> 6) * 256 + o) * 64 + cs * 8 + (kd & 7)] = f2bf(s);
}

#define W1ELEMS (5 * 128 * 256)
#define W2ELEMS (5 * 256 * 256)
__global__ void wprep_all(const float* __restrict__ W1n, const float* __restrict__ W1r,
                          const float* __restrict__ W2n, const float* __restrict__ W2r,
                          const float* __restrict__ b1, const float* __restrict__ b2,
                          ushort* __restrict__ W1c, ushort* __restrict__ W2c,
                          float* __restrict__ b1s, float* __restrict__ b2s) {
    int idx = blockIdx.x * blockDim.x + threadIdx.x;
    if (idx < W1ELEMS) {
        int p = idx / (128 * 256), rem = idx - p * (128 * 256);
        int k = rem & 127, o = rem >> 7;           // k-contiguous: coalesced reads
        float s;
        if (p == 0) {
            s = 0.f;
            for (int r = 0; r < RR; ++r) s += W1r[(size_t)r * DOUT * DIN + (long)o * DIN + k];
        } else {
            s = W1n[(size_t)(p - 1) * DOUT * DIN + (long)o * DIN + k];
        }
        store_w(W1c, p * 128 + k, o, s * 0.25f);
        return;
    }
    idx -= W1ELEMS;
    if (idx < W2ELEMS) {
        int p = idx / (256 * 256), rem = idx - p * (256 * 256);
        int k = rem & 255, o = rem >> 8;           // k-contiguous: coalesced reads
        float s;
        if (p == 0) {
            s = 0.f;
            for (int r = 0; r < RR; ++r) s += W2r[(size_t)r * DOUT * DOUT + (long)o * DOUT + k];
        } else {
            s = W2n[(size_t)(p - 1) * DOUT * DOUT + (long)o * DOUT + k];
        }
        store_w(W2c, p * 256 + k, o, s * 0.25f);
        return;
    }
    idx -= W2ELEMS;
    if (idx < 512) {
        int o = idx & 255;
        const float* b = (idx < 256) ? b1 : b2;
        float s = 0.f;
        for (int r = 0; r < RR; ++r) s += b[(long)r * 256 + o];
        ((idx < 256) ? b1s : b2s)[o] = s * 0.25f;
    }
}

// ---------------- CSR build, XCD-partitioned by dst group ----------------
__global__ __launch_bounds__(256) void deg_count(const int* __restrict__ ei,
                                                 int* __restrict__ deg) {
    const int CH = EE / 4;
    int p = blockIdx.x & 7;
    const int stride = (PBLKS / 8) * 256;
    for (int idx = (blockIdx.x >> 3) * 256 + threadIdx.x; idx < RR * CH; idx += stride) {
        int r = idx / CH, j = idx - r * CH;
        int4 d = ((const int4*)(ei + (size_t)r * 2 * EE + EE))[j];
        if (((d.x >> 8) & 7) == p) atomicAdd(&deg[r * NN + d.x], 1);
        if (((d.y >> 8) & 7) == p) atomicAdd(&deg[r * NN + d.y], 1);
        if (((d.z >> 8) & 7) == p) atomicAdd(&deg[r * NN + d.z], 1);
        if (((d.w >> 8) & 7) == p) atomicAdd(&deg[r * NN + d.w], 1);
    }
}

__global__ __launch_bounds__(256) void fill_csr(const int* __restrict__ ei,
                                                int* __restrict__ cursor,
                                                int* __restrict__ elist) {
    const int CH = EE / 4;
    int p = blockIdx.x & 7;
    const int stride = (PBLKS / 8) * 256;
    for (int idx = (blockIdx.x >> 3) * 256 + threadIdx.x; idx < RR * CH; idx += stride) {
        int r = idx / CH, j = idx - r * CH;
        int4 d = ((const int4*)(ei + (size_t)r * 2 * EE + EE))[j];
        int4 s = ((const int4*)(ei + (size_t)r * 2 * EE))[j];
        if (((d.x >> 8) & 7) == p) elist[atomicAdd(&cursor[r * NN + d.x], 1)] = s.x;
        if (((d.y >> 8) & 7) == p) elist[atomicAdd(&cursor[r * NN + d.y], 1)] = s.y;
        if (((d.z >> 8) & 7) == p) elist[atomicAdd(&cursor[r * NN + d.z], 1)] = s.z;
        if (((d.w >> 8) & 7) == p) elist[atomicAdd(&cursor[r * NN + d.w], 1)] = s.w;
    }
}

__global__ __launch_bounds__(256) void scan_part(const int* __restrict__ deg,
                                                 int* __restrict__ bsum) {
    int b = blockIdx.x, t = threadIdx.x;
    int s = 0;
    for (int i = t; i < SCAN_CHUNK; i += 256) s += deg[b * SCAN_CHUNK + i];
    for (int o = 32; o > 0; o >>= 1) s += __shfl_down(s, o);
    __shared__ int red[4];
    if ((t & 63) == 0) red[t >> 6] = s;
    __syncthreads();
    if (t == 0) bsum[b] = red[0] + red[1] + red[2] + red[3];
}

__global__ __launch_bounds__(512) void scan_top(int* __restrict__ bsum) {
    __shared__ int v[512];
    int t = threadIdx.x;
    v[t] = (t < SCAN_BLKS) ? bsum[t] : 0;
    __syncthreads();
    for (int st = 1; st < 512; st <<= 1) {
        int tmp = (t >= st) ? v[t - st] : 0;
        __syncthreads();
        v[t] += tmp;
        __syncthreads();
    }
    if (t < SCAN_BLKS) bsum[t] = (t == 0) ? 0 : v[t - 1];  // exclusive
}

// writes off[] AND re-initializes degc[] as the fill cursor
__global__ __launch_bounds__(256) void scan_final(int* __restrict__ degc,
                                                  const int* __restrict__ bsum,
                                                  int* __restrict__ off) {
    __shared__ int lv[1024];
    __shared__ int ts[256];
    int b = blockIdx.x, t = threadIdx.x;
    for (int i = t; i < 1024; i += 256)
        lv[i] = (i < SCAN_CHUNK) ? degc[b * SCAN_CHUNK + i] : 0;
    __syncthreads();
    int i0 = t * 4;
    int v0 = lv[i0], v1 = lv[i0 + 1], v2 = lv[i0 + 2], v3 = lv[i0 + 3];
    ts[t] = v0 + v1 + v2 + v3;
    __syncthreads();
    for (int st = 1; st < 256; st <<= 1) {
        int tmp = (t >= st) ? ts[t - st] : 0;
        __syncthreads();
        ts[t] += tmp;
        __syncthreads();
    }
    int run = bsum[b] + (t ? ts[t - 1] : 0);
    if (i0 < SCAN_CHUNK) {
        int base = b * SCAN_CHUNK + i0;
        off[base + 0] = run; degc[base + 0] = run; run += v0;
        off[base + 1] = run; degc[base + 1] = run; run += v1;
        off[base + 2] = run; degc[base + 2] = run; run += v2;
        off[base + 3] = run; degc[base + 3] = run; run += v3;
    }
    if (b == SCAN_BLKS - 1 && t == 255) off[NB] = bsum[b] + ts[255];
}

// ---------------- fp32 x -> compact bf16 table XB [NN][128] ----------------
__global__ void cvt_x(const float* __restrict__ x, ushort* __restrict__ XB) {
    int t = blockIdx.x * blockDim.x + threadIdx.x;
    if (t >= NN * 32) return;
    int n = t >> 5, c4 = (t & 31) * 4;
    float4 v = *(const float4*)&x[(size_t)n * 128 + c4];
    ushort4 o = {f2bf(v.x), f2bf(v.y), f2bf(v.z), f2bf(v.w)};
    *(ushort4*)&XB[(size_t)n * 128 + c4] = o;
}

// ---------------- gather (r11-proven): wave per (node,relation), 4 loads in flight ----
template <int D>
__global__ void gather_bf16(const ushort* __restrict__ feat,
                            const int* __restrict__ elist, const int* __restrict__ off,
                            ushort* __restrict__ agg, int sout, int chunk) {
    constexpr int V = D / 64;  // ushorts per lane
    int wv = blockIdx.x * 4 + (threadIdx.x >> 6);
    int lane = threadIdx.x & 63;
    if (wv >= NN * chunk) return;
    int n = wv / chunk, rl = wv - n * chunk;
    int b = rl * NN + n;
    int beg = __builtin_amdgcn_readfirstlane(off[b]);      // wave-uniform -> SGPR
    int end = __builtin_amdgcn_readfirstlane(off[b + 1]);
    float acc[V];
#pragma unroll
    for (int v = 0; v < V; ++v) acc[v] = 0.f;
    const ushort* fbase = feat + lane * V;
    int e = beg;
    for (; e + 4 <= end; e += 4) {
        int s0 = elist[e], s1 = elist[e + 1], s2 = elist[e + 2], s3 = elist[e + 3];
        if constexpr (V == 2) {
            ushort2 a0 = *(const ushort2*)(fbase + (size_t)s0 * D);
            ushort2 a1 = *(const ushort2*)(fbase + (size_t)s1 * D);
            ushort2 a2 = *(const ushort2*)(fbase + (size_t)s2 * D);
            ushort2 a3 = *(const ushort2*)(fbase + (size_t)s3 * D);
            acc[0] += (bf2f(a0.x) + bf2f(a1.x)) + (bf2f(a2.x) + bf2f(a3.x));
            acc[1] += (bf2f(a0.y) + bf2f(a1.y)) + (bf2f(a2.y) + bf2f(a3.y));
        } else {
            ushort4 a0 = *(const ushort4*)(fbase + (size_t)s0 * D);
            ushort4 a1 = *(const ushort4*)(fbase + (size_t)s1 * D);
            ushort4 a2 = *(const ushort4*)(fbase + (size_t)s2 * D);
            ushort4 a3 = *(const ushort4*)(fbase + (size_t)s3 * D);
            acc[0] += (bf2f(a0.x) + bf2f(a1.x)) + (bf2f(a2.x) + bf2f(a3.x));
            acc[1] += (bf2f(a0.y) + bf2f(a1.y)) + (bf2f(a2.y) + bf2f(a3.y));
            acc[2] += (bf2f(a0.z) + bf2f(a1.z)) + (bf2f(a2.z) + bf2f(a3.z));
            acc[3] += (bf2f(a0.w) + bf2f(a1.w)) + (bf2f(a2.w) + bf2f(a3.w));
        }
    }
    for (; e < end; ++e) {
        int s0 = elist[e];
        if constexpr (V == 2) {
            ushort2 a = *(const ushort2*)(fbase + (size_t)s0 * D);
            acc[0] += bf2f(a.x); acc[1] += bf2f(a.y);
        } else {
            ushort4 a = *(const ushort4*)(fbase + (size_t)s0 * D);
            acc[0] += bf2f(a.x); acc[1] += bf2f(a.y);
            acc[2] += bf2f(a.z); acc[3] += bf2f(a.w);
        }
    }
    ushort* op = agg + (size_t)n * sout + rl * D + lane * V;
    if constexpr (V == 2) {
        uint u = (uint)f2bf(acc[0]) | ((uint)f2bf(acc[1]) << 16);
        *(uint*)op = u;
    } else {
        uint2v u;
        u.x = (uint)f2bf(acc[0]) | ((uint)f2bf(acc[1]) << 16);
        u.y = (uint)f2bf(acc[2]) | ((uint)f2bf(acc[3]) << 16);
        *(uint2v*)op = u;
    }
}

// ============ GEMM v4: 128x256 tile, 8 waves (2x4), full dbuf 96 KB, T3-min ===========
// STAGE(t+1) issues BEFORE the MFMA cluster on tile t; single __syncthreads drain at
// iteration bottom -> loads stay in flight through compute (BW-bound, not latency).
// acc = 64 VGPR/lane (8 waves), total ~110-130 VGPR: no spill (r9), no reg-B (r13/r14),
// 2 waves/SIMD (not r8's 1). A and B both swizzled BK=64 (r11-proven, conflict-free).
// MODE 1: fused bias+l2norm+relu, bf16 out. MODE 0: bias, f32 NT out.
template <int MODE>
__global__ __launch_bounds__(512, 2) void gemm_fused(
    const ushort* __restrict__ F, int ldf, int K1,
    const ushort* __restrict__ G, int ldg, int K2,
    const ushort* __restrict__ W, const float* __restrict__ bias,
    void* __restrict__ Cout, int M) {
    __shared__ ushort lA[2][128 * 64];   // 32 KB
    __shared__ ushort lB[2][256 * 64];   // 64 KB
    const int tid = threadIdx.x;
    const int w = tid >> 6, lane = tid & 63;
    const int wr = w >> 2, wc = w & 3;       // wave grid: 2 row-halves x 4 col-quarters
    const int row0 = blockIdx.x * 128;

    f32x4 acc[4][4];
#pragma unroll
    for (int i = 0; i < 4; ++i)
#pragma unroll
        for (int j = 0; j < 4; ++j) acc[i][j] = {0.f, 0.f, 0.f, 0.f};

    const int arow = lane >> 3;
    const int asrc = ((lane & 7) ^ arow) << 3;  // pre-swizzled source chunk
    const int ldst = lane * 8;
    const ushort* aF[2]; const ushort* aG[2];
#pragma unroll
    for (int c = 0; c < 2; ++c) {
        int rg = row0 + w * 16 + c * 8 + arow;
        if (rg > M - 1) rg = M - 1;
        aF[c] = F + (size_t)rg * ldf + asrc;
        aG[c] = G + (size_t)rg * ldg + asrc;
    }
    const int nt = (K1 + K2) >> 6;

    // 6 gllds per wave per tile: 2 A (rows w*16..w*16+15) + 4 B (cols w*32..w*32+31)
    auto STAGE = [&](int buf, int t) {
        int kb = t << 6;
#pragma unroll
        for (int c = 0; c < 2; ++c) {
            const ushort* src = (kb < K1) ? (aF[c] + kb) : (aG[c] + (kb - K1));
            ld_g2l16(src, &lA[buf][(w * 16 + c * 8) * 64 + ldst]);
        }
        const ushort* wb = W + (size_t)t * (256 * 64);
#pragma unroll
        for (int c = 0; c < 4; ++c)
            ld_g2l16(wb + (w * 32 + c * 8) * 64 + ldst,
                     &lB[buf][(w * 32 + c * 8) * 64 + ldst]);
    };

    STAGE(0, 0);
    __syncthreads();   // drain tile-0 loads

    int cur = 0;
    for (int t = 0; t < nt; ++t) {
        if (t + 1 < nt) STAGE(cur ^ 1, t + 1);   // issue next tile BEFORE compute
        __builtin_amdgcn_s_setprio(1);
#pragma unroll
        for (int ks = 0; ks < 2; ++ks) {
            const int co = (((ks * 4 + (lane >> 4)) ^ (lane & 7)) << 3);  // swizzled read
            short8 af[4];
#pragma unroll
            for (int rf = 0; rf < 4; ++rf)
                af[rf] = *(const short8*)&lA[cur]
                             [(wr * 64 + rf * 16 + (lane & 15)) * 64 + co];
#pragma unroll
            for (int cf = 0; cf < 4; ++cf) {
                short8 bf8 = *(const short8*)&lB[cur]
                                 [(wc * 64 + cf * 16 + (lane & 15)) * 64 + co];
#pragma unroll
                for (int rf = 0; rf < 4; ++rf)
                    acc[rf][cf] = __builtin_amdgcn_mfma_f32_16x16x32_bf16(
                        af[rf], bf8, acc[rf][cf], 0, 0, 0);
            }
        }
        __builtin_amdgcn_s_setprio(0);
        __syncthreads();   // vmcnt0+lgkm0+barrier: t+1 loads landed during MFMA
        cur ^= 1;
    }

    // bias
#pragma unroll
    for (int cf = 0; cf < 4; ++cf) {
        float badd = bias[wc * 64 + cf * 16 + (lane & 15)];
#pragma unroll
        for (int rf = 0; rf < 4; ++rf)
#pragma unroll
            for (int m = 0; m < 4; ++m) acc[rf][cf][m] += badd;
    }

    if constexpr (MODE == 0) {
        float* Cf = (float*)Cout;
#pragma unroll
        for (int cf = 0; cf < 4; ++cf) {
            int col = wc * 64 + cf * 16 + (lane & 15);
#pragma unroll
            for (int rf = 0; rf < 4; ++rf)
#pragma unroll
                for (int m = 0; m < 4; ++m) {
                    int r = row0 + wr * 64 + rf * 16 + (lane >> 4) * 4 + m;
                    if (r < M)
                        __builtin_nontemporal_store(acc[rf][cf][m],
                                                    &Cf[(size_t)r * 256 + col]);
                }
        }
    } else {
        // row sumsq: 16-lane shuffle + cross-wave (4 col-quarters) via LDS alias on lA[0]
        float* rs = (float*)&lA[0][0];  // [4 wc][128] floats = 2 KB
        float ss[4][4];
#pragma unroll
        for (int rf = 0; rf < 4; ++rf)
#pragma unroll
            for (int m = 0; m < 4; ++m) {
                float s = 0.f;
#pragma unroll
                for (int cf = 0; cf < 4; ++cf) s += acc[rf][cf][m] * acc[rf][cf][m];
#pragma unroll
                for (int o = 1; o < 16; o <<= 1) s += __shfl_xor(s, o);
                ss[rf][m] = s;
            }
        // final loop iteration ended with __syncthreads(): lA no longer read
        if ((lane & 15) == 0) {
#pragma unroll
            for (int rf = 0; rf < 4; ++rf)
#pragma unroll
                for (int m = 0; m < 4; ++m)
                    rs[wc * 128 + wr * 64 + rf * 16 + (lane >> 4) * 4 + m] = ss[rf][m];
        }
        __syncthreads();
        uint* HBw = (uint*)Cout;
#pragma unroll
        for (int rf = 0; rf < 4; ++rf)
#pragma unroll
            for (int m = 0; m < 4; ++m) {
                int tr = wr * 64 + rf * 16 + (lane >> 4) * 4 + m;
                float tot = rs[tr] + rs[128 + tr] + rs[256 + tr] + rs[384 + tr];
                float inv = 1.0f / fmaxf(sqrtf(tot), 1e-12f);
                int r = row0 + tr;
#pragma unroll
                for (int cf = 0; cf < 4; ++cf) {
                    float v = fmaxf(acc[rf][cf][m] * inv, 0.f);
                    uint u = f2bf(v);
                    uint pu = __shfl_xor(u, 1);
                    if (!(lane & 1) && r < M)
                        HBw[(size_t)r * 128 + ((wc * 64 + cf * 16 + (lane & 15)) >> 1)] =
                            u | (pu << 16);
                }
            }
    }
}

extern "C" void kernel_launch(void* const* d_in, const int* in_sizes, int n_in,
                              void* d_out, int out_size, void* d_ws, size_t ws_size,
                              hipStream_t stream) {
    const float* x   = (const float*)d_in[0];
    const int*   ei  = (const int*)d_in[1];
    const float* W1n = (const float*)d_in[2];
    const float* b1  = (const float*)d_in[3];
    const float* W1r = (const float*)d_in[4];
    const float* W2n = (const float*)d_in[5];
    const float* b2  = (const float*)d_in[6];
    const float* W2r = (const float*)d_in[7];

    // ---- ws layout (XB overlaid on G2: lifetimes disjoint) ----
    ushort* HB  = (ushort*)d_ws;                       // [NN][256] bf16 h table
    ushort* G1  = HB + (size_t)NN * 256;               // [NN][512] layer-1 aggs
    ushort* G2  = G1 + (size_t)NN * 512;               // [NN][1024] layer-2 aggs
    ushort* XB  = G2;                                  // [NN][128] bf16 x (dies before G2 lives)
    int* elist  = (int*)(G2 + (size_t)NN * 1024);      // RR*EE
    int* degc   = elist + (size_t)RR * EE;             // NB (deg -> cursor)
    int* off    = degc + NB;                           // NB+1
    int* bsum   = off + NB + 1;                        // 512
    ushort* W1c = (ushort*)(bsum + 512);               // 640*256
    ushort* W2c = W1c + 640 * 256;                     // 1280*256
    float* b1s  = (float*)(W2c + 1280 * 256);
    float* b2s  = b1s + 256;

    // ---- CSR build (XCD-partitioned) ----
    hipMemsetAsync(degc, 0, (size_t)NB * sizeof(int), stream);
    deg_count<<<PBLKS, 256, 0, stream>>>(ei, degc);
    scan_part<<<SCAN_BLKS, 256, 0, stream>>>(degc, bsum);
    scan_top<<<1, 512, 0, stream>>>(bsum);
    scan_final<<<SCAN_BLKS, 256, 0, stream>>>(degc, bsum, off);
    fill_csr<<<PBLKS, 256, 0, stream>>>(ei, degc, elist);

    // ---- weight/bias prep (one kernel) + x conversion ----
    {
        int total = W1ELEMS + W2ELEMS + 512;
        wprep_all<<<(total + 255) / 256, 256, 0, stream>>>(W1n, W1r, W2n, W2r, b1, b2,
                                                           W1c, W2c, b1s, b2s);
    }
    cvt_x<<<(NN * 32 + 255) / 256, 256, 0, stream>>>(x, XB);

    const int ggrid = (NN + 127) / 128;   // 782

    // ---- layer 1: HB = relu(l2norm(0.25*(x·W1r_sum + Σ_r agg_r(x)·W1n_r) + b1s)) ----
    gather_bf16<128><<<NN, 256, 0, stream>>>(XB, elist, off, G1, 512, RR);
    gemm_fused<1><<<ggrid, 512, 0, stream>>>(XB, 128, 128, G1, 512, 512, W1c, b1s, HB, NN);

    // ---- layer 2: out = 0.25*(h·W2r_sum + Σ_r agg_r(h)·W2n_r) + b2s ----
    gather_bf16<256><<<NN, 256, 0, stream>>>(HB, elist, off, G2, 1024, RR);
    gemm_fused<0><<<ggrid, 512, 0, stream>>>(HB, 256, 256, G2, 1024, 1024, W2c, b2s,
                                             d_out, NN);
}

// Round 17
// 713.764 us; speedup vs baseline: 1.0878x; 1.0878x over previous
//
#include <hip/hip_runtime.h>
#include <hip/hip_bf16.h>

#define NN 100000
#define DIN 128
#define DOUT 256
#define RR 4
#define EE 600000
#define NB (RR * NN)
#define SCAN_BLKS 400
#define SCAN_CHUNK 1000
#define PBLKS 2048          // CSR-build blocks; bid&7 = XCD partition (round-robin map)

typedef __attribute__((ext_vector_type(4))) float f32x4;
typedef __attribute__((ext_vector_type(8))) short short8;
typedef __attribute__((ext_vector_type(2))) uint uint2v;

__device__ __forceinline__ float bf2f(ushort u) {
    union { unsigned int i; float f; } v; v.i = ((unsigned int)u) << 16; return v.f;
}
__device__ __forceinline__ ushort f2bf(float f) {
    union { float f; unsigned int i; } v; v.f = f;
    unsigned int r = v.i + 0x7fff + ((v.i >> 16) & 1);  // RNE
    return (ushort)(r >> 16);
}

__device__ __forceinline__ void ld_g2l16(const void* g, void* l) {
    __builtin_amdgcn_global_load_lds(
        (const __attribute__((address_space(1))) void*)g,
        (__attribute__((address_space(3))) void*)l, 16, 0, 0);
}

// ---------------- consolidated weight/bias prep ----------------
// W layout (r11-proven, SWIZZLED for LDS-staged B): logical W[kd][o] = 0.25*sum;
// block kd>>6, chunk c=(kd>>3)&7 stored at slot c^(o&7), elem kd&7.
__device__ __forceinline__ void store_w(ushort* W, int kd, int o, float s) {
    int cs = ((kd >> 3) & 7) ^ (o & 7);
    W[((size_t)(kd >> 6) * 256 + o) * 64 + cs * 8 + (kd & 7)] = f2bf(s);
}

#define W1ELEMS (5 * 128 * 256)
#define W2ELEMS (5 * 256 * 256)
__global__ void wprep_all(const float* __restrict__ W1n, const float* __restrict__ W1r,
                          const float* __restrict__ W2n, const float* __restrict__ W2r,
                          const float* __restrict__ b1, const float* __restrict__ b2,
                          ushort* __restrict__ W1c, ushort* __restrict__ W2c,
                          float* __restrict__ b1s, float* __restrict__ b2s) {
    int idx = blockIdx.x * blockDim.x + threadIdx.x;
    if (idx < W1ELEMS) {
        int p = idx / (128 * 256), rem = idx - p * (128 * 256);
        int k = rem & 127, o = rem >> 7;           // k-contiguous: coalesced reads
        float s;
        if (p == 0) {
            s = 0.f;
            for (int r = 0; r < RR; ++r) s += W1r[(size_t)r * DOUT * DIN + (long)o * DIN + k];
        } else {
            s = W1n[(size_t)(p - 1) * DOUT * DIN + (long)o * DIN + k];
        }
        store_w(W1c, p * 128 + k, o, s * 0.25f);
        return;
    }
    idx -= W1ELEMS;
    if (idx < W2ELEMS) {
        int p = idx / (256 * 256), rem = idx - p * (256 * 256);
        int k = rem & 255, o = rem >> 8;           // k-contiguous: coalesced reads
        float s;
        if (p == 0) {
            s = 0.f;
            for (int r = 0; r < RR; ++r) s += W2r[(size_t)r * DOUT * DOUT + (long)o * DOUT + k];
        } else {
            s = W2n[(size_t)(p - 1) * DOUT * DOUT + (long)o * DOUT + k];
        }
        store_w(W2c, p * 256 + k, o, s * 0.25f);
        return;
    }
    idx -= W2ELEMS;
    if (idx < 512) {
        int o = idx & 255;
        const float* b = (idx < 256) ? b1 : b2;
        float s = 0.f;
        for (int r = 0; r < RR; ++r) s += b[(long)r * 256 + o];
        ((idx < 256) ? b1s : b2s)[o] = s * 0.25f;
    }
}

// ---------------- CSR build, XCD-partitioned by dst group ----------------
__global__ __launch_bounds__(256) void deg_count(const int* __restrict__ ei,
                                                 int* __restrict__ deg) {
    const int CH = EE / 4;
    int p = blockIdx.x & 7;
    const int stride = (PBLKS / 8) * 256;
    for (int idx = (blockIdx.x >> 3) * 256 + threadIdx.x; idx < RR * CH; idx += stride) {
        int r = idx / CH, j = idx - r * CH;
        int4 d = ((const int4*)(ei + (size_t)r * 2 * EE + EE))[j];
        if (((d.x >> 8) & 7) == p) atomicAdd(&deg[r * NN + d.x], 1);
        if (((d.y >> 8) & 7) == p) atomicAdd(&deg[r * NN + d.y], 1);
        if (((d.z >> 8) & 7) == p) atomicAdd(&deg[r * NN + d.z], 1);
        if (((d.w >> 8) & 7) == p) atomicAdd(&deg[r * NN + d.w], 1);
    }
}

__global__ __launch_bounds__(256) void fill_csr(const int* __restrict__ ei,
                                                int* __restrict__ cursor,
                                                int* __restrict__ elist) {
    const int CH = EE / 4;
    int p = blockIdx.x & 7;
    const int stride = (PBLKS / 8) * 256;
    for (int idx = (blockIdx.x >> 3) * 256 + threadIdx.x; idx < RR * CH; idx += stride) {
        int r = idx / CH, j = idx - r * CH;
        int4 d = ((const int4*)(ei + (size_t)r * 2 * EE + EE))[j];
        int4 s = ((const int4*)(ei + (size_t)r * 2 * EE))[j];
        if (((d.x >> 8) & 7) == p) elist[atomicAdd(&cursor[r * NN + d.x], 1)] = s.x;
        if (((d.y >> 8) & 7) == p) elist[atomicAdd(&cursor[r * NN + d.y], 1)] = s.y;
        if (((d.z >> 8) & 7) == p) elist[atomicAdd(&cursor[r * NN + d.z], 1)] = s.z;
        if (((d.w >> 8) & 7) == p) elist[atomicAdd(&cursor[r * NN + d.w], 1)] = s.w;
    }
}

__global__ __launch_bounds__(256) void scan_part(const int* __restrict__ deg,
                                                 int* __restrict__ bsum) {
    int b = blockIdx.x, t = threadIdx.x;
    int s = 0;
    for (int i = t; i < SCAN_CHUNK; i += 256) s += deg[b * SCAN_CHUNK + i];
    for (int o = 32; o > 0; o >>= 1) s += __shfl_down(s, o);
    __shared__ int red[4];
    if ((t & 63) == 0) red[t >> 6] = s;
    __syncthreads();
    if (t == 0) bsum[b] = red[0] + red[1] + red[2] + red[3];
}

__global__ __launch_bounds__(512) void scan_top(int* __restrict__ bsum) {
    __shared__ int v[512];
    int t = threadIdx.x;
    v[t] = (t < SCAN_BLKS) ? bsum[t] : 0;
    __syncthreads();
    for (int st = 1; st < 512; st <<= 1) {
        int tmp = (t >= st) ? v[t - st] : 0;
        __syncthreads();
        v[t] += tmp;
        __syncthreads();
    }
    if (t < SCAN_BLKS) bsum[t] = (t == 0) ? 0 : v[t - 1];  // exclusive
}

// writes off[] AND re-initializes degc[] as the fill cursor
__global__ __launch_bounds__(256) void scan_final(int* __restrict__ degc,
                                                  const int* __restrict__ bsum,
                                                  int* __restrict__ off) {
    __shared__ int lv[1024];
    __shared__ int ts[256];
    int b = blockIdx.x, t = threadIdx.x;
    for (int i = t; i < 1024; i += 256)
        lv[i] = (i < SCAN_CHUNK) ? degc[b * SCAN_CHUNK + i] : 0;
    __syncthreads();
    int i0 = t * 4;
    int v0 = lv[i0], v1 = lv[i0 + 1], v2 = lv[i0 + 2], v3 = lv[i0 + 3];
    ts[t] = v0 + v1 + v2 + v3;
    __syncthreads();
    for (int st = 1; st < 256; st <<= 1) {
        int tmp = (t >= st) ? ts[t - st] : 0;
        __syncthreads();
        ts[t] += tmp;
        __syncthreads();
    }
    int run = bsum[b] + (t ? ts[t - 1] : 0);
    if (i0 < SCAN_CHUNK) {
        int base = b * SCAN_CHUNK + i0;
        off[base + 0] = run; degc[base + 0] = run; run += v0;
        off[base + 1] = run; degc[base + 1] = run; run += v1;
        off[base + 2] = run; degc[base + 2] = run; run += v2;
        off[base + 3] = run; degc[base + 3] = run; run += v3;
    }
    if (b == SCAN_BLKS - 1 && t == 255) off[NB] = bsum[b] + ts[255];
}

// ---------------- fp32 x -> compact bf16 table XB [NN][128] ----------------
__global__ void cvt_x(const float* __restrict__ x, ushort* __restrict__ XB) {
    int t = blockIdx.x * blockDim.x + threadIdx.x;
    if (t >= NN * 32) return;
    int n = t >> 5, c4 = (t & 31) * 4;
    float4 v = *(const float4*)&x[(size_t)n * 128 + c4];
    ushort4 o = {f2bf(v.x), f2bf(v.y), f2bf(v.z), f2bf(v.w)};
    *(ushort4*)&XB[(size_t)n * 128 + c4] = o;
}

// ---------------- gather (r11-proven): wave per (node,relation), 4 loads in flight ----
template <int D>
__global__ void gather_bf16(const ushort* __restrict__ feat,
                            const int* __restrict__ elist, const int* __restrict__ off,
                            ushort* __restrict__ agg, int sout, int chunk) {
    constexpr int V = D / 64;  // ushorts per lane
    int wv = blockIdx.x * 4 + (threadIdx.x >> 6);
    int lane = threadIdx.x & 63;
    if (wv >= NN * chunk) return;
    int n = wv / chunk, rl = wv - n * chunk;
    int b = rl * NN + n;
    int beg = __builtin_amdgcn_readfirstlane(off[b]);      // wave-uniform -> SGPR
    int end = __builtin_amdgcn_readfirstlane(off[b + 1]);
    float acc[V];
#pragma unroll
    for (int v = 0; v < V; ++v) acc[v] = 0.f;
    const ushort* fbase = feat + lane * V;
    int e = beg;
    for (; e + 4 <= end; e += 4) {
        int s0 = elist[e], s1 = elist[e + 1], s2 = elist[e + 2], s3 = elist[e + 3];
        if constexpr (V == 2) {
            ushort2 a0 = *(const ushort2*)(fbase + (size_t)s0 * D);
            ushort2 a1 = *(const ushort2*)(fbase + (size_t)s1 * D);
            ushort2 a2 = *(const ushort2*)(fbase + (size_t)s2 * D);
            ushort2 a3 = *(const ushort2*)(fbase + (size_t)s3 * D);
            acc[0] += (bf2f(a0.x) + bf2f(a1.x)) + (bf2f(a2.x) + bf2f(a3.x));
            acc[1] += (bf2f(a0.y) + bf2f(a1.y)) + (bf2f(a2.y) + bf2f(a3.y));
        } else {
            ushort4 a0 = *(const ushort4*)(fbase + (size_t)s0 * D);
            ushort4 a1 = *(const ushort4*)(fbase + (size_t)s1 * D);
            ushort4 a2 = *(const ushort4*)(fbase + (size_t)s2 * D);
            ushort4 a3 = *(const ushort4*)(fbase + (size_t)s3 * D);
            acc[0] += (bf2f(a0.x) + bf2f(a1.x)) + (bf2f(a2.x) + bf2f(a3.x));
            acc[1] += (bf2f(a0.y) + bf2f(a1.y)) + (bf2f(a2.y) + bf2f(a3.y));
            acc[2] += (bf2f(a0.z) + bf2f(a1.z)) + (bf2f(a2.z) + bf2f(a3.z));
            acc[3] += (bf2f(a0.w) + bf2f(a1.w)) + (bf2f(a2.w) + bf2f(a3.w));
        }
    }
    for (; e < end; ++e) {
        int s0 = elist[e];
        if constexpr (V == 2) {
            ushort2 a = *(const ushort2*)(fbase + (size_t)s0 * D);
            acc[0] += bf2f(a.x); acc[1] += bf2f(a.y);
        } else {
            ushort4 a = *(const ushort4*)(fbase + (size_t)s0 * D);
            acc[0] += bf2f(a.x); acc[1] += bf2f(a.y);
            acc[2] += bf2f(a.z); acc[3] += bf2f(a.w);
        }
    }
    ushort* op = agg + (size_t)n * sout + rl * D + lane * V;
    if constexpr (V == 2) {
        uint u = (uint)f2bf(acc[0]) | ((uint)f2bf(acc[1]) << 16);
        *(uint*)op = u;
    } else {
        uint2v u;
        u.x = (uint)f2bf(acc[0]) | ((uint)f2bf(acc[1]) << 16);
        u.y = (uint)f2bf(acc[2]) | ((uint)f2bf(acc[3]) << 16);
        *(uint2v*)op = u;
    }
}

// ================= unified GEMM (r11-proven): 128x256, 4 waves, 48 KB LDS =============
// A = concat(F [M,ldf] K1 cols, G [M,ldg] K2 cols); W swizzled [Kt/64][256][64].
// Simple 2-barrier loop; VGPR~152 at (256,2) -> 3 blocks/CU naturally. 5/5 structural
// pipeline variants (r8/r9/r13/r14/r16) regressed: each traded occupancy or exposed a
// serial stall. Cross-block wave overlap (m114) is the winning latency-hiding here.
// MODE 1: fused bias+l2norm+relu, bf16 out. MODE 0: bias, f32 NT out.
template <int MODE>
__global__ __launch_bounds__(256, 2) void gemm_fused(
    const ushort* __restrict__ F, int ldf, int K1,
    const ushort* __restrict__ G, int ldg, int K2,
    const ushort* __restrict__ W, const float* __restrict__ bias,
    void* __restrict__ Cout, int M) {
    __shared__ ushort lA[128 * 64];   // 16 KB
    __shared__ ushort lB[256 * 64];   // 32 KB
    const int tid = threadIdx.x;
    const int w = tid >> 6, lane = tid & 63;
    const int row0 = blockIdx.x * 128;

    f32x4 acc[8][4];
#pragma unroll
    for (int i = 0; i < 8; ++i)
#pragma unroll
        for (int j = 0; j < 4; ++j) acc[i][j] = {0.f, 0.f, 0.f, 0.f};

    const int arow = lane >> 3;
    const int asrc = ((lane & 7) ^ arow) << 3;  // pre-swizzled source chunk
    const int ldst = lane * 8;
    const ushort* aF[4]; const ushort* aG[4];
#pragma unroll
    for (int c = 0; c < 4; ++c) {
        int rg = row0 + w * 32 + c * 8 + arow;
        if (rg > M - 1) rg = M - 1;
        aF[c] = F + (size_t)rg * ldf + asrc;
        aG[c] = G + (size_t)rg * ldg + asrc;
    }
    const int nt = (K1 + K2) >> 6;

    for (int t = 0; t < nt; ++t) {
        __syncthreads();
        int kb = t << 6;
#pragma unroll
        for (int c = 0; c < 4; ++c) {
            const ushort* src = (kb < K1) ? (aF[c] + kb) : (aG[c] + (kb - K1));
            ld_g2l16(src, &lA[(w * 32 + c * 8) * 64 + ldst]);
        }
        const ushort* wb = W + (size_t)t * (256 * 64);
#pragma unroll
        for (int c = 0; c < 8; ++c)
            ld_g2l16(wb + (w * 64 + c * 8) * 64 + ldst, &lB[(w * 64 + c * 8) * 64 + ldst]);
        asm volatile("s_waitcnt vmcnt(0)" ::: "memory");
        __syncthreads();
        __builtin_amdgcn_s_setprio(1);
#pragma unroll
        for (int ks = 0; ks < 2; ++ks) {
            const int co = (((ks * 4 + (lane >> 4)) ^ (lane & 7)) << 3);
            short8 af[8];
#pragma unroll
            for (int rf = 0; rf < 8; ++rf)
                af[rf] = *(const short8*)&lA[(rf * 16 + (lane & 15)) * 64 + co];
#pragma unroll
            for (int cf = 0; cf < 4; ++cf) {
                short8 bf8 = *(const short8*)&lB[(w * 64 + cf * 16 + (lane & 15)) * 64 + co];
#pragma unroll
                for (int rf = 0; rf < 8; ++rf)
                    acc[rf][cf] = __builtin_amdgcn_mfma_f32_16x16x32_bf16(
                        af[rf], bf8, acc[rf][cf], 0, 0, 0);
            }
        }
        __builtin_amdgcn_s_setprio(0);
    }

    // bias
#pragma unroll
    for (int cf = 0; cf < 4; ++cf) {
        float badd = bias[w * 64 + cf * 16 + (lane & 15)];
#pragma unroll
        for (int rf = 0; rf < 8; ++rf)
#pragma unroll
            for (int m = 0; m < 4; ++m) acc[rf][cf][m] += badd;
    }

    if constexpr (MODE == 0) {
        float* Cf = (float*)Cout;
#pragma unroll
        for (int cf = 0; cf < 4; ++cf) {
            int col = w * 64 + cf * 16 + (lane & 15);
#pragma unroll
            for (int rf = 0; rf < 8; ++rf)
#pragma unroll
                for (int m = 0; m < 4; ++m) {
                    int r = row0 + rf * 16 + (lane >> 4) * 4 + m;
                    if (r < M)
                        __builtin_nontemporal_store(acc[rf][cf][m],
                                                    &Cf[(size_t)r * 256 + col]);
                }
        }
    } else {
        // row sumsq (16-lane shuffle + cross-wave via LDS aliased onto lA) -> norm -> relu
        float* rs = (float*)lA;  // [4][128] floats = 2 KB, reused after barrier
        float ss[8][4];
#pragma unroll
        for (int rf = 0; rf < 8; ++rf)
#pragma unroll
            for (int m = 0; m < 4; ++m) {
                float s = 0.f;
#pragma unroll
                for (int cf = 0; cf < 4; ++cf) s += acc[rf][cf][m] * acc[rf][cf][m];
#pragma unroll
                for (int o = 1; o < 16; o <<= 1) s += __shfl_xor(s, o);
                ss[rf][m] = s;
            }
        __syncthreads();  // all waves done reading lA (last tile) before aliasing
        if ((lane & 15) == 0) {
#pragma unroll
            for (int rf = 0; rf < 8; ++rf)
#pragma unroll
                for (int m = 0; m < 4; ++m)
                    rs[w * 128 + rf * 16 + (lane >> 4) * 4 + m] = ss[rf][m];
        }
        __syncthreads();
        uint* HBw = (uint*)Cout;
#pragma unroll
        for (int rf = 0; rf < 8; ++rf)
#pragma unroll
            for (int m = 0; m < 4; ++m) {
                int tr = rf * 16 + (lane >> 4) * 4 + m;
                float tot = rs[tr] + rs[128 + tr] + rs[256 + tr] + rs[384 + tr];
                float inv = 1.0f / fmaxf(sqrtf(tot), 1e-12f);
                int r = row0 + tr;
#pragma unroll
                for (int cf = 0; cf < 4; ++cf) {
                    float v = fmaxf(acc[rf][cf][m] * inv, 0.f);
                    uint u = f2bf(v);
                    uint pu = __shfl_xor(u, 1);
                    if (!(lane & 1) && r < M)
                        HBw[(size_t)r * 128 + ((w * 64 + cf * 16 + (lane & 15)) >> 1)] =
                            u | (pu << 16);
                }
            }
    }
}

extern "C" void kernel_launch(void* const* d_in, const int* in_sizes, int n_in,
                              void* d_out, int out_size, void* d_ws, size_t ws_size,
                              hipStream_t stream) {
    const float* x   = (const float*)d_in[0];
    const int*   ei  = (const int*)d_in[1];
    const float* W1n = (const float*)d_in[2];
    const float* b1  = (const float*)d_in[3];
    const float* W1r = (const float*)d_in[4];
    const float* W2n = (const float*)d_in[5];
    const float* b2  = (const float*)d_in[6];
    const float* W2r = (const float*)d_in[7];

    // ---- ws layout (XB overlaid on G2: lifetimes disjoint) ----
    ushort* HB  = (ushort*)d_ws;                       // [NN][256] bf16 h table
    ushort* G1  = HB + (size_t)NN * 256;               // [NN][512] layer-1 aggs
    ushort* G2  = G1 + (size_t)NN * 512;               // [NN][1024] layer-2 aggs
    ushort* XB  = G2;                                  // [NN][128] bf16 x (dies before G2 lives)
    int* elist  = (int*)(G2 + (size_t)NN * 1024);      // RR*EE
    int* degc   = elist + (size_t)RR * EE;             // NB (deg -> cursor)
    int* off    = degc + NB;                           // NB+1
    int* bsum   = off + NB + 1;                        // 512
    ushort* W1c = (ushort*)(bsum + 512);               // 640*256
    ushort* W2c = W1c + 640 * 256;                     // 1280*256
    float* b1s  = (float*)(W2c + 1280 * 256);
    float* b2s  = b1s + 256;

    // ---- CSR build (XCD-partitioned) ----
    hipMemsetAsync(degc, 0, (size_t)NB * sizeof(int), stream);
    deg_count<<<PBLKS, 256, 0, stream>>>(ei, degc);
    scan_part<<<SCAN_BLKS, 256, 0, stream>>>(degc, bsum);
    scan_top<<<1, 512, 0, stream>>>(bsum);
    scan_final<<<SCAN_BLKS, 256, 0, stream>>>(degc, bsum, off);
    fill_csr<<<PBLKS, 256, 0, stream>>>(ei, degc, elist);

    // ---- weight/bias prep (one kernel) + x conversion ----
    {
        int total = W1ELEMS + W2ELEMS + 512;
        wprep_all<<<(total + 255) / 256, 256, 0, stream>>>(W1n, W1r, W2n, W2r, b1, b2,
                                                           W1c, W2c, b1s, b2s);
    }
    cvt_x<<<(NN * 32 + 255) / 256, 256, 0, stream>>>(x, XB);

    const int ggrid = (NN + 127) / 128;   // 782

    // ---- layer 1: HB = relu(l2norm(0.25*(x·W1r_sum + Σ_r agg_r(x)·W1n_r) + b1s)) ----
    gather_bf16<128><<<NN, 256, 0, stream>>>(XB, elist, off, G1, 512, RR);
    gemm_fused<1><<<ggrid, 256, 0, stream>>>(XB, 128, 128, G1, 512, 512, W1c, b1s, HB, NN);

    // ---- layer 2: out = 0.25*(h·W2r_sum + Σ_r agg_r(h)·W2n_r) + b2s ----
    gather_bf16<256><<<NN, 256, 0, stream>>>(HB, elist, off, G2, 1024, RR);
    gemm_fused<0><<<ggrid, 256, 0, stream>>>(HB, 256, 256, G2, 1024, 1024, W2c, b2s,
                                             d_out, NN);
}